// Round 11
// baseline (175.935 us; speedup 1.0000x reference)
//
#include <hip/hip_runtime.h>
#include <hip/hip_bf16.h>

typedef __attribute__((ext_vector_type(4))) float f32x4;
typedef __attribute__((ext_vector_type(16))) float f32x16;
typedef __attribute__((ext_vector_type(8))) short short8;

static constexpr int Ssz = 2048;
static constexpr int Dsz = 1024;

__device__ __forceinline__ unsigned short f2bf(float f){
  union { float f; unsigned u; } c; c.f = f;
  unsigned r = c.u + 0x7fffu + ((c.u >> 16) & 1u);
  return (unsigned short)(r >> 16);
}

__device__ __forceinline__ void gl2lds16(const void* g, void* l){
  __builtin_amdgcn_global_load_lds(
    (const __attribute__((address_space(1))) unsigned int*)g,
    (__attribute__((address_space(3))) unsigned int*)l, 16, 0, 0);
}

__device__ __forceinline__ unsigned cvtpk(float lo, float hi){
  unsigned r;
  asm("v_cvt_pk_bf16_f32 %0, %1, %2" : "=v"(r) : "v"(lo), "v"(hi));
  return r;
}

__device__ __forceinline__ void permswap(unsigned &a, unsigned &b){
  asm volatile("v_permlane32_swap_b32 %0, %1" : "+v"(a), "+v"(b));
}

__device__ __forceinline__ float xmax64(float x){
  float a = x, b;
  asm volatile("v_mov_b32 %0, %1" : "=v"(b) : "v"(a));
  asm volatile("v_permlane32_swap_b32 %0, %1" : "+v"(a), "+v"(b));
  return fmaxf(a, b);
}
__device__ __forceinline__ float xsum64(float x){
  float a = x, b;
  asm volatile("v_mov_b32 %0, %1" : "=v"(b) : "v"(a));
  asm volatile("v_permlane32_swap_b32 %0, %1" : "+v"(a), "+v"(b));
  return a + b;
}

// ---------------- fp32 -> bf16 elementwise (8/thread) ----------------
__global__ void cvt_kernel(const float* __restrict__ in, unsigned short* __restrict__ out, int n){
  int i = (blockIdx.x * 256 + threadIdx.x) * 8;
  if (i >= n) return;
  float4 a = *(const float4*)(in + i);
  float4 b = *(const float4*)(in + i + 4);
  short8 o;
  o[0]=(short)f2bf(a.x); o[1]=(short)f2bf(a.y); o[2]=(short)f2bf(a.z); o[3]=(short)f2bf(a.w);
  o[4]=(short)f2bf(b.x); o[5]=(short)f2bf(b.y); o[6]=(short)f2bf(b.z); o[7]=(short)f2bf(b.w);
  *(short8*)(out + i) = o;
}

// ---------------- fp32 [R][C] -> bf16 [C][R] transpose ----------------
__global__ void transpose_kernel(const float* __restrict__ in, unsigned short* __restrict__ out,
                                 int R, int C){
  __shared__ float tile[32][33];
  int c0 = blockIdx.x * 32, r0 = blockIdx.y * 32;
  int tx = threadIdx.x, ty = threadIdx.y;
  #pragma unroll
  for (int k = 0; k < 4; ++k)
    tile[ty + 8*k][tx] = in[(size_t)(r0 + ty + 8*k) * C + c0 + tx];
  __syncthreads();
  #pragma unroll
  for (int k = 0; k < 4; ++k)
    out[(size_t)(c0 + ty + 8*k) * R + r0 + tx] = f2bf(tile[tx][ty + 8*k]);
}

// ---------------- bf16 GEMM: C[M][N] = A[M][K] * Bt[N][K]^T + bias ----------------
// mode 0: scatter to Q (exp2-prescaled), K, Vt. mode 1: fp32 out. (R3-proven, 80.5us)
#define BM 128
#define BN 128
#define BKg 64

__global__ __launch_bounds__(256, 2)
void gemm_bt(const unsigned short* __restrict__ A, const unsigned short* __restrict__ Bt,
             int M, int N, int K,
             const float* __restrict__ bias, int mode,
             unsigned short* __restrict__ Qp, unsigned short* __restrict__ Kp,
             unsigned short* __restrict__ Vtp, float* __restrict__ Out)
{
  __shared__ unsigned short ldsA[BM * BKg];
  __shared__ unsigned short ldsB[BN * BKg];
  const int tid = threadIdx.x;
  const int wid = tid >> 6;
  const int lane = tid & 63;
  const int lr = lane & 15, lg = lane >> 4;
  const int wr = wid >> 1, wc = wid & 1;
  const int m0 = blockIdx.y * BM, n0 = blockIdx.x * BN;

  const f32x4 vzero = {0.f, 0.f, 0.f, 0.f};
  f32x4 acc[4][4];
  #pragma unroll
  for (int i = 0; i < 4; ++i)
    #pragma unroll
    for (int j = 0; j < 4; ++j) acc[i][j] = vzero;

  for (int k0 = 0; k0 < K; k0 += BKg){
    __syncthreads();
    #pragma unroll
    for (int it = 0; it < 4; ++it){
      int c = it * 256 + tid;
      int row = c >> 3;
      int sc = (c & 7) ^ (row & 7);
      gl2lds16(A  + (size_t)(m0 + row) * K + k0 + sc * 8,
               (char*)ldsA + (it * 256 + wid * 64) * 16);
      gl2lds16(Bt + (size_t)(n0 + row) * K + k0 + sc * 8,
               (char*)ldsB + (it * 256 + wid * 64) * 16);
    }
    __syncthreads();
    #pragma unroll
    for (int kc = 0; kc < 2; ++kc){
      short8 af[4], bfr[4];
      #pragma unroll
      for (int i = 0; i < 4; ++i){
        int row = wr * 64 + i * 16 + lr;
        int off = row * 128 + lg * 16 + kc * 64;
        off ^= (row & 7) << 4;
        af[i] = *(const short8*)((const char*)ldsA + off);
      }
      #pragma unroll
      for (int j = 0; j < 4; ++j){
        int row = wc * 64 + j * 16 + lr;
        int off = row * 128 + lg * 16 + kc * 64;
        off ^= (row & 7) << 4;
        bfr[j] = *(const short8*)((const char*)ldsB + off);
      }
      #pragma unroll
      for (int i = 0; i < 4; ++i)
        #pragma unroll
        for (int j = 0; j < 4; ++j)
          acc[i][j] = __builtin_amdgcn_mfma_f32_16x16x32_bf16(af[i], bfr[j], acc[i][j], 0, 0, 0);
    }
  }

  if (mode == 0){
    // Q pre-scaled by 1/sqrt(HD) * log2(e): attention works in exp2 domain
    const float qscale = 0.125f * 1.4426950408889634f;
    #pragma unroll
    for (int i = 0; i < 4; ++i)
      #pragma unroll
      for (int j = 0; j < 4; ++j)
        #pragma unroll
        for (int r = 0; r < 4; ++r){
          int gm = m0 + wr * 64 + i * 16 + lg * 4 + r;
          int gn = n0 + wc * 64 + j * 16 + lr;
          float v = acc[i][j][r] + bias[gn];
          int which = gn >> 10;
          int h = (gn >> 6) & 15;
          int hd = gn & 63;
          int b = gm >> 11;
          int s = gm & 2047;
          size_t bh = (size_t)(b * 16 + h);
          if (which == 0)      Qp[(bh * Ssz + s) * 64 + hd] = f2bf(v * qscale);
          else if (which == 1) Kp[(bh * Ssz + s) * 64 + hd] = f2bf(v);
          else                 Vtp[(bh * 64 + hd) * Ssz + s] = f2bf(v);
        }
  } else {
    #pragma unroll
    for (int i = 0; i < 4; ++i)
      #pragma unroll
      for (int j = 0; j < 4; ++j)
        #pragma unroll
        for (int r = 0; r < 4; ++r){
          int gm = m0 + wr * 64 + i * 16 + lg * 4 + r;
          int gn = n0 + wc * 64 + j * 16 + lr;
          Out[(size_t)gm * N + gn] = acc[i][j][r] + bias[gn];
        }
  }
}

// ---------------- causal flash attention, swapped-QK 32x32, KVBLK=128, merged pair ----------------
// grid (8,64), 4 waves/block, XCD-local bh grouping. Block owns q-tiles qx and 15-qx
// but sweeps K ONCE (0..15-qx) with TWO online-softmax states: state A (qt=qx) active
// for kt<=qx, state B (qt=15-qx) always. Staging drops 17 -> (16-qx) tiles (avg -26%)
// and barrier count likewise; MFMA count unchanged.
__global__ __launch_bounds__(256, 2)
void attn_kernel(const unsigned short* __restrict__ Qp, const unsigned short* __restrict__ Kp,
                 const unsigned short* __restrict__ Vtp, unsigned short* __restrict__ Att)
{
  __shared__ unsigned short ldsK[2][8192];
  __shared__ unsigned short ldsV[2][8192];
  const int tid = threadIdx.x;
  const int wid = tid >> 6;
  const int lane = tid & 63;
  const int lq = lane & 31;      // this lane's query column
  const int hi = lane >> 5;

  // XCD-aware remap: each XCD owns 8 heads (4MB K/V = its whole L2)
  const int flat = (int)blockIdx.x + 8 * (int)blockIdx.y;
  const int xcd = flat & 7;
  const int i6  = flat >> 3;
  const int bh  = xcd * 8 + (i6 >> 3);
  const int qx  = i6 & 7;
  const int b = bh >> 4, hh = bh & 15;

  const int qtA = qx, qtB = 15 - qx;
  const int q0wA = qtA * 128 + wid * 32;
  const int q0wB = qtB * 128 + wid * 32;
  const int qaA = q0wA + lq, qaB = q0wB + lq;
  const int ntB = qtB + 1;                 // tiles to sweep (covers A's range too)

  short8 qfA[4], qfB[4];
  {
    const unsigned short* QbA = Qp + ((size_t)bh * Ssz + q0wA + lq) * 64 + hi * 8;
    const unsigned short* QbB = Qp + ((size_t)bh * Ssz + q0wB + lq) * 64 + hi * 8;
    #pragma unroll
    for (int ks = 0; ks < 4; ++ks){
      qfA[ks] = *(const short8*)(QbA + ks * 16);
      qfB[ks] = *(const short8*)(QbB + ks * 16);
    }
  }

  f32x16 OtA[2], OtB[2];
  #pragma unroll
  for (int d = 0; d < 2; ++d)
    #pragma unroll
    for (int r = 0; r < 16; ++r){ OtA[d][r] = 0.f; OtB[d][r] = 0.f; }
  float mA = -3e38f, lA = 0.f, mB = -3e38f, lB = 0.f;

  // stage one 128-key tile (8 gl2lds/thread: 4 K + 4 V)
  auto STAGE = [&](int kt, int buf){
    #pragma unroll
    for (int it = 0; it < 4; ++it){
      int c = it * 256 + tid;
      int rowK = c >> 3, scK = (c & 7) ^ (rowK & 7);
      gl2lds16(Kp + ((size_t)bh * Ssz + kt * 128 + rowK) * 64 + scK * 8,
               (char*)&ldsK[buf][0] + c * 16);
      int rowV = c >> 4, scV = (c & 15) ^ (rowV & 7);
      gl2lds16(Vtp + ((size_t)bh * 64 + rowV) * Ssz + kt * 128 + scV * 8,
               (char*)&ldsV[buf][0] + c * 16);
    }
  };

  // one 128-key tile for one state
  auto PROCESS = [&](int kt, const char* Kb, const char* Vb, const short8* qf,
                     int qtX, int qaX, f32x16* Ot, float& mrun, float& lsum){
    f32x16 S[4];
    #pragma unroll
    for (int kb = 0; kb < 4; ++kb)
      #pragma unroll
      for (int r = 0; r < 16; ++r) S[kb][r] = 0.f;
    #pragma unroll
    for (int ks = 0; ks < 4; ++ks){
      int col = ks * 32 + hi * 16;
      #pragma unroll
      for (int kb = 0; kb < 4; ++kb){
        int row = kb * 32 + lq;
        short8 kfr = *(const short8*)(Kb + ((row * 128 + col) ^ ((row & 7) << 4)));
        S[kb] = __builtin_amdgcn_mfma_f32_32x32x16_bf16(kfr, qf[ks], S[kb], 0, 0, 0);
      }
    }

    if (kt == qtX){
      #pragma unroll
      for (int r = 0; r < 16; ++r){
        int keyb = kt * 128 + (r & 3) + ((r >> 2) << 3) + 4 * hi;
        #pragma unroll
        for (int kb = 0; kb < 4; ++kb)
          if (keyb + kb * 32 > qaX) S[kb][r] = -3e38f;
      }
    }

    float t16[16];
    #pragma unroll
    for (int r = 0; r < 16; ++r)
      t16[r] = fmaxf(fmaxf(S[0][r], S[1][r]), fmaxf(S[2][r], S[3][r]));
    float t8[8];
    #pragma unroll
    for (int r = 0; r < 8; ++r) t8[r] = fmaxf(t16[r], t16[r + 8]);
    float t4[4];
    #pragma unroll
    for (int r = 0; r < 4; ++r) t4[r] = fmaxf(t8[r], t8[r + 4]);
    float pmax = fmaxf(fmaxf(t4[0], t4[1]), fmaxf(t4[2], t4[3]));
    pmax = xmax64(pmax);

    // defer-max (T13)
    if (!__all(pmax - mrun <= 8.0f)){
      float mn = fmaxf(mrun, pmax);
      float scl = __builtin_amdgcn_exp2f(mrun - mn);
      mrun = mn;
      lsum *= scl;
      #pragma unroll
      for (int d = 0; d < 2; ++d)
        #pragma unroll
        for (int r = 0; r < 16; ++r) Ot[d][r] *= scl;
    }

    #pragma unroll
    for (int kb = 0; kb < 4; ++kb)
      #pragma unroll
      for (int r = 0; r < 16; ++r)
        S[kb][r] = __builtin_amdgcn_exp2f(S[kb][r] - mrun);

    #pragma unroll
    for (int r = 0; r < 16; ++r)
      t16[r] = (S[0][r] + S[1][r]) + (S[2][r] + S[3][r]);
    #pragma unroll
    for (int r = 0; r < 8; ++r) t8[r] = t16[r] + t16[r + 8];
    #pragma unroll
    for (int r = 0; r < 4; ++r) t4[r] = t8[r] + t8[r + 4];
    float psum = (t4[0] + t4[1]) + (t4[2] + t4[3]);
    psum = xsum64(psum);
    lsum += psum;

    #pragma unroll
    for (int s = 0; s < 8; ++s){
      const int kb = s >> 1, s1 = s & 1;
      unsigned u0 = cvtpk(S[kb][8 * s1 + 0], S[kb][8 * s1 + 1]);
      unsigned u1 = cvtpk(S[kb][8 * s1 + 2], S[kb][8 * s1 + 3]);
      unsigned u2 = cvtpk(S[kb][8 * s1 + 4], S[kb][8 * s1 + 5]);
      unsigned u3 = cvtpk(S[kb][8 * s1 + 6], S[kb][8 * s1 + 7]);
      permswap(u0, u2);
      permswap(u1, u3);
      union { unsigned u[4]; short8 s8; } pb;
      pb.u[0] = u0; pb.u[1] = u1; pb.u[2] = u2; pb.u[3] = u3;

      int col = s * 32 + hi * 16;   // V^T row is 256B
      int r0 = lq, r1 = 32 + lq;
      short8 v0 = *(const short8*)(Vb + (r0 * 256 + (col ^ ((r0 & 7) << 4))));
      short8 v1 = *(const short8*)(Vb + (r1 * 256 + (col ^ ((r1 & 7) << 4))));
      Ot[0] = __builtin_amdgcn_mfma_f32_32x32x16_bf16(v0, pb.s8, Ot[0], 0, 0, 0);
      Ot[1] = __builtin_amdgcn_mfma_f32_32x32x16_bf16(v1, pb.s8, Ot[1], 0, 0, 0);
    }
  };

  STAGE(0, 0);
  __syncthreads();

  #pragma unroll 1
  for (int kt = 0; kt < ntB; ++kt){
    const int cur = kt & 1;
    if (kt + 1 < ntB) STAGE(kt + 1, cur ^ 1);
    const char* Kb = (const char*)&ldsK[cur][0];
    const char* Vb = (const char*)&ldsV[cur][0];
    if (kt <= qtA) PROCESS(kt, Kb, Vb, qfA, qtA, qaA, OtA, mA, lA);
    PROCESS(kt, Kb, Vb, qfB, qtB, qaB, OtB, mB, lB);
    __syncthreads();
  }

  // epilogues: O^T/lsum -> per-wave swizzled LDS transpose -> coalesced stores.
  // ep region is wave-exclusive; only wave-local lgkmcnt ordering needed.
  unsigned short* ep = &ldsK[0][0] + wid * 2048;   // 4KB per wave
  auto EPI = [&](const f32x16* Ot, float lsum, int q0w){
    float inv = 1.0f / lsum;
    #pragma unroll
    for (int d = 0; d < 2; ++d)
      #pragma unroll
      for (int g = 0; g < 4; ++g){
        int r = g * 4;
        uint2 w2;
        w2.x = cvtpk(Ot[d][r] * inv,     Ot[d][r + 1] * inv);
        w2.y = cvtpk(Ot[d][r + 2] * inv, Ot[d][r + 3] * inv);
        int base = d * 32 + g * 8 + 4 * hi;           // d-elems base..base+3
        int byte = lq * 128 + ((base * 2) ^ ((lq & 7) << 4));
        *(uint2*)((char*)ep + byte) = w2;
      }
    asm volatile("s_waitcnt lgkmcnt(0)" ::: "memory");
    __builtin_amdgcn_sched_barrier(0);
    #pragma unroll
    for (int ii = 0; ii < 4; ++ii){
      int qr = ii * 8 + (lane >> 3);
      int cc = lane & 7;
      int byte = qr * 128 + ((cc * 16) ^ ((qr & 7) << 4));
      short8 vv = *(const short8*)((const char*)ep + byte);
      *(short8*)(Att + ((size_t)(b * Ssz + q0w + qr)) * Dsz + hh * 64 + cc * 8) = vv;
    }
    asm volatile("s_waitcnt lgkmcnt(0)" ::: "memory");
    __builtin_amdgcn_sched_barrier(0);
  };
  EPI(OtA, lA, q0wA);
  EPI(OtB, lB, q0wB);
}

extern "C" void kernel_launch(void* const* d_in, const int* in_sizes, int n_in,
                              void* d_out, int out_size, void* d_ws, size_t ws_size,
                              hipStream_t stream) {
  const float* x    = (const float*)d_in[0];
  const float* Wqkv = (const float*)d_in[1];
  const float* bqkv = (const float*)d_in[2];
  const float* Wout = (const float*)d_in[3];
  const float* bout = (const float*)d_in[4];
  float* out = (float*)d_out;

  unsigned short* xb    = (unsigned short*)d_ws;                 // 8192*1024
  unsigned short* wqkvT = xb    + (size_t)8192 * 1024;           // 3072*1024
  unsigned short* woutT = wqkvT + (size_t)3072 * 1024;           // 1024*1024
  unsigned short* Qb    = woutT + (size_t)1024 * 1024;           // [B,H,S,HD]
  unsigned short* Kb    = Qb    + (size_t)8388608;
  unsigned short* Vtb   = Kb    + (size_t)8388608;
  unsigned short* Attb  = Vtb   + (size_t)8388608;

  cvt_kernel<<<4096, 256, 0, stream>>>(x, xb, 8388608);
  transpose_kernel<<<dim3(96, 32), dim3(32, 8), 0, stream>>>(Wqkv, wqkvT, 1024, 3072);
  transpose_kernel<<<dim3(32, 32), dim3(32, 8), 0, stream>>>(Wout, woutT, 1024, 1024);
  gemm_bt<<<dim3(24, 64), 256, 0, stream>>>(xb, wqkvT, 8192, 3072, 1024,
                                            bqkv, 0, Qb, Kb, Vtb, nullptr);
  attn_kernel<<<dim3(8, 64), 256, 0, stream>>>(Qb, Kb, Vtb, Attb);
  gemm_bt<<<dim3(8, 64), 256, 0, stream>>>(Attb, woutT, 8192, 1024, 1024,
                                           bout, 1, nullptr, nullptr, nullptr, out);
}

// Round 12
// 168.080 us; speedup vs baseline: 1.0467x; 1.0467x over previous
//
#include <hip/hip_runtime.h>
#include <hip/hip_bf16.h>

typedef __attribute__((ext_vector_type(4))) float f32x4;
typedef __attribute__((ext_vector_type(16))) float f32x16;
typedef __attribute__((ext_vector_type(8))) short short8;

static constexpr int Ssz = 2048;
static constexpr int Dsz = 1024;

__device__ __forceinline__ unsigned short f2bf(float f){
  union { float f; unsigned u; } c; c.f = f;
  unsigned r = c.u + 0x7fffu + ((c.u >> 16) & 1u);
  return (unsigned short)(r >> 16);
}

__device__ __forceinline__ void gl2lds16(const void* g, void* l){
  __builtin_amdgcn_global_load_lds(
    (const __attribute__((address_space(1))) unsigned int*)g,
    (__attribute__((address_space(3))) unsigned int*)l, 16, 0, 0);
}

__device__ __forceinline__ unsigned cvtpk(float lo, float hi){
  unsigned r;
  asm("v_cvt_pk_bf16_f32 %0, %1, %2" : "=v"(r) : "v"(lo), "v"(hi));
  return r;
}

__device__ __forceinline__ void permswap(unsigned &a, unsigned &b){
  asm volatile("v_permlane32_swap_b32 %0, %1" : "+v"(a), "+v"(b));
}

__device__ __forceinline__ float xmax64(float x){
  float a = x, b;
  asm volatile("v_mov_b32 %0, %1" : "=v"(b) : "v"(a));
  asm volatile("v_permlane32_swap_b32 %0, %1" : "+v"(a), "+v"(b));
  return fmaxf(a, b);
}
__device__ __forceinline__ float xsum64(float x){
  float a = x, b;
  asm volatile("v_mov_b32 %0, %1" : "=v"(b) : "v"(a));
  asm volatile("v_permlane32_swap_b32 %0, %1" : "+v"(a), "+v"(b));
  return a + b;
}

// ---------------- fused prep: x->bf16 cvt + Wqkv^T + Wout^T, one dispatch ----------------
// grid: [0,4096) cvt; [4096,7168) Wqkv transpose tiles (96x32); [7168,8192) Wout (32x32)
__global__ void prep_kernel(const float* __restrict__ x, unsigned short* __restrict__ xb,
                            const float* __restrict__ Wqkv, unsigned short* __restrict__ wqkvT,
                            const float* __restrict__ Wout, unsigned short* __restrict__ woutT)
{
  __shared__ float tile[32][33];
  const int bid = blockIdx.x;
  const int tid = threadIdx.x;

  if (bid < 4096){
    int i = (bid * 256 + tid) * 8;
    float4 a = *(const float4*)(x + i);
    float4 b = *(const float4*)(x + i + 4);
    short8 o;
    o[0]=(short)f2bf(a.x); o[1]=(short)f2bf(a.y); o[2]=(short)f2bf(a.z); o[3]=(short)f2bf(a.w);
    o[4]=(short)f2bf(b.x); o[5]=(short)f2bf(b.y); o[6]=(short)f2bf(b.z); o[7]=(short)f2bf(b.w);
    *(short8*)(xb + i) = o;
    return;
  }

  const float* in; unsigned short* out; int R, C, c0, r0;
  if (bid < 4096 + 3072){
    int t = bid - 4096;
    in = Wqkv; out = wqkvT; R = 1024; C = 3072;
    c0 = (t % 96) * 32; r0 = (t / 96) * 32;
  } else {
    int t = bid - 4096 - 3072;
    in = Wout; out = woutT; R = 1024; C = 1024;
    c0 = (t % 32) * 32; r0 = (t / 32) * 32;
  }
  int tx = tid & 31, ty = tid >> 5;   // 32 x 8
  #pragma unroll
  for (int k = 0; k < 4; ++k)
    tile[ty + 8*k][tx] = in[(size_t)(r0 + ty + 8*k) * C + c0 + tx];
  __syncthreads();
  #pragma unroll
  for (int k = 0; k < 4; ++k)
    out[(size_t)(c0 + ty + 8*k) * R + r0 + tx] = f2bf(tile[tx][ty + 8*k]);
}

// ---------------- bf16 GEMM: C[M][N] = A[M][K] * Bt[N][K]^T + bias ----------------
// mode 0: scatter to Q (exp2-prescaled), K, Vt. mode 1: fp32 out. (R3-proven, 80.5us)
#define BM 128
#define BN 128
#define BKg 64

__global__ __launch_bounds__(256, 4)
void gemm_bt(const unsigned short* __restrict__ A, const unsigned short* __restrict__ Bt,
             int M, int N, int K,
             const float* __restrict__ bias, int mode,
             unsigned short* __restrict__ Qp, unsigned short* __restrict__ Kp,
             unsigned short* __restrict__ Vtp, float* __restrict__ Out)
{
  __shared__ unsigned short ldsA[BM * BKg];
  __shared__ unsigned short ldsB[BN * BKg];
  const int tid = threadIdx.x;
  const int wid = tid >> 6;
  const int lane = tid & 63;
  const int lr = lane & 15, lg = lane >> 4;
  const int wr = wid >> 1, wc = wid & 1;
  const int m0 = blockIdx.y * BM, n0 = blockIdx.x * BN;

  const f32x4 vzero = {0.f, 0.f, 0.f, 0.f};
  f32x4 acc[4][4];
  #pragma unroll
  for (int i = 0; i < 4; ++i)
    #pragma unroll
    for (int j = 0; j < 4; ++j) acc[i][j] = vzero;

  for (int k0 = 0; k0 < K; k0 += BKg){
    __syncthreads();
    #pragma unroll
    for (int it = 0; it < 4; ++it){
      int c = it * 256 + tid;
      int row = c >> 3;
      int sc = (c & 7) ^ (row & 7);
      gl2lds16(A  + (size_t)(m0 + row) * K + k0 + sc * 8,
               (char*)ldsA + (it * 256 + wid * 64) * 16);
      gl2lds16(Bt + (size_t)(n0 + row) * K + k0 + sc * 8,
               (char*)ldsB + (it * 256 + wid * 64) * 16);
    }
    __syncthreads();
    #pragma unroll
    for (int kc = 0; kc < 2; ++kc){
      short8 af[4], bfr[4];
      #pragma unroll
      for (int i = 0; i < 4; ++i){
        int row = wr * 64 + i * 16 + lr;
        int off = row * 128 + lg * 16 + kc * 64;
        off ^= (row & 7) << 4;
        af[i] = *(const short8*)((const char*)ldsA + off);
      }
      #pragma unroll
      for (int j = 0; j < 4; ++j){
        int row = wc * 64 + j * 16 + lr;
        int off = row * 128 + lg * 16 + kc * 64;
        off ^= (row & 7) << 4;
        bfr[j] = *(const short8*)((const char*)ldsB + off);
      }
      #pragma unroll
      for (int i = 0; i < 4; ++i)
        #pragma unroll
        for (int j = 0; j < 4; ++j)
          acc[i][j] = __builtin_amdgcn_mfma_f32_16x16x32_bf16(af[i], bfr[j], acc[i][j], 0, 0, 0);
    }
  }

  if (mode == 0){
    // Q pre-scaled by 1/sqrt(HD) * log2(e): attention works in exp2 domain
    const float qscale = 0.125f * 1.4426950408889634f;
    #pragma unroll
    for (int i = 0; i < 4; ++i)
      #pragma unroll
      for (int j = 0; j < 4; ++j)
        #pragma unroll
        for (int r = 0; r < 4; ++r){
          int gm = m0 + wr * 64 + i * 16 + lg * 4 + r;
          int gn = n0 + wc * 64 + j * 16 + lr;
          float v = acc[i][j][r] + bias[gn];
          int which = gn >> 10;
          int h = (gn >> 6) & 15;
          int hd = gn & 63;
          int b = gm >> 11;
          int s = gm & 2047;
          size_t bh = (size_t)(b * 16 + h);
          if (which == 0)      Qp[(bh * Ssz + s) * 64 + hd] = f2bf(v * qscale);
          else if (which == 1) Kp[(bh * Ssz + s) * 64 + hd] = f2bf(v);
          else                 Vtp[(bh * 64 + hd) * Ssz + s] = f2bf(v);
        }
  } else {
    #pragma unroll
    for (int i = 0; i < 4; ++i)
      #pragma unroll
      for (int j = 0; j < 4; ++j)
        #pragma unroll
        for (int r = 0; r < 4; ++r){
          int gm = m0 + wr * 64 + i * 16 + lg * 4 + r;
          int gn = n0 + wc * 64 + j * 16 + lr;
          Out[(size_t)gm * N + gn] = acc[i][j][r] + bias[gn];
        }
  }
}

// ---------------- causal flash attention, swapped-QK 32x32, KVBLK=128 (R10-proven) ----------------
// grid (8,64), 4 waves/block, XCD-local bh grouping. K-tile 128 keys; 17 barrier-drains
// per block-job pair. LDS: K 128x64 + V^T 64x128, double-buffered = 64KB/block.
__global__ __launch_bounds__(256, 2)
void attn_kernel(const unsigned short* __restrict__ Qp, const unsigned short* __restrict__ Kp,
                 const unsigned short* __restrict__ Vtp, unsigned short* __restrict__ Att)
{
  __shared__ unsigned short ldsK[2][8192];
  __shared__ unsigned short ldsV[2][8192];
  const int tid = threadIdx.x;
  const int wid = tid >> 6;
  const int lane = tid & 63;
  const int lq = lane & 31;      // this lane's query column
  const int hi = lane >> 5;

  // XCD-aware remap: each XCD owns 8 heads (4MB K/V = its whole L2)
  const int flat = (int)blockIdx.x + 8 * (int)blockIdx.y;
  const int xcd = flat & 7;
  const int i6  = flat >> 3;
  const int bh  = xcd * 8 + (i6 >> 3);
  const int qx  = i6 & 7;
  const int b = bh >> 4, hh = bh & 15;

  #pragma unroll 1
  for (int job = 0; job < 2; ++job){
    const int qt = job ? (15 - qx) : qx;      // q-tile of 128 rows
    const int q0w = qt * 128 + wid * 32;
    const int qa = q0w + lq;
    const int nt = qt + 1;                    // 128-key tiles

    short8 qf[4];
    {
      const unsigned short* Qb = Qp + ((size_t)bh * Ssz + q0w + lq) * 64 + hi * 8;
      #pragma unroll
      for (int ks = 0; ks < 4; ++ks) qf[ks] = *(const short8*)(Qb + ks * 16);
    }

    f32x16 Ot[2];
    #pragma unroll
    for (int d = 0; d < 2; ++d)
      #pragma unroll
      for (int r = 0; r < 16; ++r) Ot[d][r] = 0.f;
    float mrun = -3e38f, lsum = 0.f;

    // stage one 128-key tile: 8 loads/thr (4 K + 4 V)
    auto STAGE = [&](int kt, int buf){
      #pragma unroll
      for (int it = 0; it < 4; ++it){
        int c = it * 256 + tid;
        int rowK = c >> 3, scK = (c & 7) ^ (rowK & 7);
        gl2lds16(Kp + ((size_t)bh * Ssz + kt * 128 + rowK) * 64 + scK * 8,
                 (char*)&ldsK[buf][0] + c * 16);
        int rowV = c >> 4, scV = (c & 15) ^ (rowV & 7);
        gl2lds16(Vtp + ((size_t)bh * 64 + rowV) * Ssz + kt * 128 + scV * 8,
                 (char*)&ldsV[buf][0] + c * 16);
      }
    };

    STAGE(0, 0);
    __syncthreads();

    #pragma unroll 1
    for (int kt = 0; kt < nt; ++kt){
      const int cur = kt & 1;
      if (kt + 1 < nt) STAGE(kt + 1, cur ^ 1);

      if (kt * 128 <= q0w + 31){   // wave not fully masked
        const char* Kb = (const char*)&ldsK[cur][0];
        const char* Vb = (const char*)&ldsV[cur][0];

        // S^T = K · Q^T over 4 kb-blocks of 32 keys
        f32x16 S[4];
        #pragma unroll
        for (int kb = 0; kb < 4; ++kb)
          #pragma unroll
          for (int r = 0; r < 16; ++r) S[kb][r] = 0.f;
        #pragma unroll
        for (int ks = 0; ks < 4; ++ks){
          int col = ks * 32 + hi * 16;
          #pragma unroll
          for (int kb = 0; kb < 4; ++kb){
            int row = kb * 32 + lq;
            short8 kfr = *(const short8*)(Kb + ((row * 128 + col) ^ ((row & 7) << 4)));
            S[kb] = __builtin_amdgcn_mfma_f32_32x32x16_bf16(kfr, qf[ks], S[kb], 0, 0, 0);
          }
        }

        // causal mask (fires only on kt == qt)
        if (kt * 128 + 127 > q0w){
          #pragma unroll
          for (int r = 0; r < 16; ++r){
            int keyb = kt * 128 + (r & 3) + ((r >> 2) << 3) + 4 * hi;
            #pragma unroll
            for (int kb = 0; kb < 4; ++kb)
              if (keyb + kb * 32 > qa) S[kb][r] = -3e38f;
          }
        }

        float t16[16];
        #pragma unroll
        for (int r = 0; r < 16; ++r)
          t16[r] = fmaxf(fmaxf(S[0][r], S[1][r]), fmaxf(S[2][r], S[3][r]));
        float t8[8];
        #pragma unroll
        for (int r = 0; r < 8; ++r) t8[r] = fmaxf(t16[r], t16[r + 8]);
        float t4[4];
        #pragma unroll
        for (int r = 0; r < 4; ++r) t4[r] = fmaxf(t8[r], t8[r + 4]);
        float pmax = fmaxf(fmaxf(t4[0], t4[1]), fmaxf(t4[2], t4[3]));
        pmax = xmax64(pmax);

        // defer-max (T13)
        if (!__all(pmax - mrun <= 8.0f)){
          float mn = fmaxf(mrun, pmax);
          float scl = __builtin_amdgcn_exp2f(mrun - mn);
          mrun = mn;
          lsum *= scl;
          #pragma unroll
          for (int d = 0; d < 2; ++d)
            #pragma unroll
            for (int r = 0; r < 16; ++r) Ot[d][r] *= scl;
        }

        #pragma unroll
        for (int kb = 0; kb < 4; ++kb)
          #pragma unroll
          for (int r = 0; r < 16; ++r)
            S[kb][r] = __builtin_amdgcn_exp2f(S[kb][r] - mrun);

        #pragma unroll
        for (int r = 0; r < 16; ++r)
          t16[r] = (S[0][r] + S[1][r]) + (S[2][r] + S[3][r]);
        #pragma unroll
        for (int r = 0; r < 8; ++r) t8[r] = t16[r] + t16[r + 8];
        #pragma unroll
        for (int r = 0; r < 4; ++r) t4[r] = t8[r] + t8[r + 4];
        float psum = (t4[0] + t4[1]) + (t4[2] + t4[3]);
        psum = xsum64(psum);
        lsum += psum;

        // PV over 8 key-steps of 16
        #pragma unroll
        for (int s = 0; s < 8; ++s){
          const int kb = s >> 1, s1 = s & 1;
          unsigned u0 = cvtpk(S[kb][8 * s1 + 0], S[kb][8 * s1 + 1]);
          unsigned u1 = cvtpk(S[kb][8 * s1 + 2], S[kb][8 * s1 + 3]);
          unsigned u2 = cvtpk(S[kb][8 * s1 + 4], S[kb][8 * s1 + 5]);
          unsigned u3 = cvtpk(S[kb][8 * s1 + 6], S[kb][8 * s1 + 7]);
          permswap(u0, u2);
          permswap(u1, u3);
          union { unsigned u[4]; short8 s8; } pb;
          pb.u[0] = u0; pb.u[1] = u1; pb.u[2] = u2; pb.u[3] = u3;

          int col = s * 32 + hi * 16;   // V^T row is 256B
          int r0 = lq, r1 = 32 + lq;
          short8 v0 = *(const short8*)(Vb + (r0 * 256 + (col ^ ((r0 & 7) << 4))));
          short8 v1 = *(const short8*)(Vb + (r1 * 256 + (col ^ ((r1 & 7) << 4))));
          Ot[0] = __builtin_amdgcn_mfma_f32_32x32x16_bf16(v0, pb.s8, Ot[0], 0, 0, 0);
          Ot[1] = __builtin_amdgcn_mfma_f32_32x32x16_bf16(v1, pb.s8, Ot[1], 0, 0, 0);
        }
      }
      __syncthreads();
    }

    // epilogue: O^T/lsum -> per-wave swizzled LDS transpose -> coalesced stores
    float inv = 1.0f / lsum;
    unsigned short* ep = &ldsK[0][0] + wid * 2048;   // 4KB per wave
    #pragma unroll
    for (int d = 0; d < 2; ++d)
      #pragma unroll
      for (int g = 0; g < 4; ++g)
        #pragma unroll
        for (int cp = 0; cp < 2; ++cp){
          int r = g * 4 + cp * 2;
          unsigned w = cvtpk(Ot[d][r] * inv, Ot[d][r + 1] * inv);
          int dd = d * 32 + g * 8 + 4 * hi + cp * 2;
          int byte = lq * 128 + ((dd * 2) ^ ((lq & 7) << 4));
          *(unsigned*)((char*)ep + byte) = w;
        }
    __syncthreads();
    #pragma unroll
    for (int ii = 0; ii < 4; ++ii){
      int qr = ii * 8 + (lane >> 3);
      int cc = lane & 7;
      int byte = qr * 128 + ((cc * 16) ^ ((qr & 7) << 4));
      short8 vv = *(const short8*)((const char*)ep + byte);
      *(short8*)(Att + ((size_t)(b * Ssz + q0w + qr)) * Dsz + hh * 64 + cc * 8) = vv;
    }
    __syncthreads();   // protect epilogue scratch before next job's staging
  }
}

extern "C" void kernel_launch(void* const* d_in, const int* in_sizes, int n_in,
                              void* d_out, int out_size, void* d_ws, size_t ws_size,
                              hipStream_t stream) {
  const float* x    = (const float*)d_in[0];
  const float* Wqkv = (const float*)d_in[1];
  const float* bqkv = (const float*)d_in[2];
  const float* Wout = (const float*)d_in[3];
  const float* bout = (const float*)d_in[4];
  float* out = (float*)d_out;

  unsigned short* xb    = (unsigned short*)d_ws;                 // 8192*1024
  unsigned short* wqkvT = xb    + (size_t)8192 * 1024;           // 3072*1024
  unsigned short* woutT = wqkvT + (size_t)3072 * 1024;           // 1024*1024
  unsigned short* Qb    = woutT + (size_t)1024 * 1024;           // [B,H,S,HD]
  unsigned short* Kb    = Qb    + (size_t)8388608;
  unsigned short* Vtb   = Kb    + (size_t)8388608;
  unsigned short* Attb  = Vtb   + (size_t)8388608;

  prep_kernel<<<8192, 256, 0, stream>>>(x, xb, Wqkv, wqkvT, Wout, woutT);
  gemm_bt<<<dim3(24, 64), 256, 0, stream>>>(xb, wqkvT, 8192, 3072, 1024,
                                            bqkv, 0, Qb, Kb, Vtb, nullptr);
  attn_kernel<<<dim3(8, 64), 256, 0, stream>>>(Qb, Kb, Vtb, Attb);
  gemm_bt<<<dim3(8, 64), 256, 0, stream>>>(Attb, woutT, 8192, 1024, 1024,
                                           bout, 1, nullptr, nullptr, nullptr, out);
}

// Round 13
// 167.829 us; speedup vs baseline: 1.0483x; 1.0015x over previous
//
#include <hip/hip_runtime.h>
#include <hip/hip_bf16.h>

typedef __attribute__((ext_vector_type(4))) float f32x4;
typedef __attribute__((ext_vector_type(16))) float f32x16;
typedef __attribute__((ext_vector_type(8))) short short8;

static constexpr int Ssz = 2048;
static constexpr int Dsz = 1024;

__device__ __forceinline__ unsigned short f2bf(float f){
  union { float f; unsigned u; } c; c.f = f;
  unsigned r = c.u + 0x7fffu + ((c.u >> 16) & 1u);
  return (unsigned short)(r >> 16);
}

__device__ __forceinline__ void gl2lds16(const void* g, void* l){
  __builtin_amdgcn_global_load_lds(
    (const __attribute__((address_space(1))) unsigned int*)g,
    (__attribute__((address_space(3))) unsigned int*)l, 16, 0, 0);
}

__device__ __forceinline__ unsigned cvtpk(float lo, float hi){
  unsigned r;
  asm("v_cvt_pk_bf16_f32 %0, %1, %2" : "=v"(r) : "v"(lo), "v"(hi));
  return r;
}

__device__ __forceinline__ void permswap(unsigned &a, unsigned &b){
  asm volatile("v_permlane32_swap_b32 %0, %1" : "+v"(a), "+v"(b));
}

__device__ __forceinline__ float xmax64(float x){
  float a = x, b;
  asm volatile("v_mov_b32 %0, %1" : "=v"(b) : "v"(a));
  asm volatile("v_permlane32_swap_b32 %0, %1" : "+v"(a), "+v"(b));
  return fmaxf(a, b);
}
__device__ __forceinline__ float xsum64(float x){
  float a = x, b;
  asm volatile("v_mov_b32 %0, %1" : "=v"(b) : "v"(a));
  asm volatile("v_permlane32_swap_b32 %0, %1" : "+v"(a), "+v"(b));
  return a + b;
}

// ---------------- fused prep: x->bf16 cvt + Wqkv^T + Wout^T, one dispatch ----------------
__global__ void prep_kernel(const float* __restrict__ x, unsigned short* __restrict__ xb,
                            const float* __restrict__ Wqkv, unsigned short* __restrict__ wqkvT,
                            const float* __restrict__ Wout, unsigned short* __restrict__ woutT)
{
  __shared__ float tile[32][33];
  const int bid = blockIdx.x;
  const int tid = threadIdx.x;

  if (bid < 4096){
    int i = (bid * 256 + tid) * 8;
    float4 a = *(const float4*)(x + i);
    float4 b = *(const float4*)(x + i + 4);
    short8 o;
    o[0]=(short)f2bf(a.x); o[1]=(short)f2bf(a.y); o[2]=(short)f2bf(a.z); o[3]=(short)f2bf(a.w);
    o[4]=(short)f2bf(b.x); o[5]=(short)f2bf(b.y); o[6]=(short)f2bf(b.z); o[7]=(short)f2bf(b.w);
    *(short8*)(xb + i) = o;
    return;
  }

  const float* in; unsigned short* out; int R, C, c0, r0;
  if (bid < 4096 + 3072){
    int t = bid - 4096;
    in = Wqkv; out = wqkvT; R = 1024; C = 3072;
    c0 = (t % 96) * 32; r0 = (t / 96) * 32;
  } else {
    int t = bid - 4096 - 3072;
    in = Wout; out = woutT; R = 1024; C = 1024;
    c0 = (t % 32) * 32; r0 = (t / 32) * 32;
  }
  int tx = tid & 31, ty = tid >> 5;   // 32 x 8
  #pragma unroll
  for (int k = 0; k < 4; ++k)
    tile[ty + 8*k][tx] = in[(size_t)(r0 + ty + 8*k) * C + c0 + tx];
  __syncthreads();
  #pragma unroll
  for (int k = 0; k < 4; ++k)
    out[(size_t)(c0 + ty + 8*k) * R + r0 + tx] = f2bf(tile[tx][ty + 8*k]);
}

// ---------------- bf16 GEMM: C[M][N] = A[M][K] * Bt[N][K]^T + bias ----------------
// mode 0: scatter to Q (exp2-prescaled), K, Vt. mode 1: fp32 out.
#define BM 128
#define BN 128
#define BKg 64

__global__ __launch_bounds__(256, 4)
void gemm_bt(const unsigned short* __restrict__ A, const unsigned short* __restrict__ Bt,
             int M, int N, int K,
             const float* __restrict__ bias, int mode,
             unsigned short* __restrict__ Qp, unsigned short* __restrict__ Kp,
             unsigned short* __restrict__ Vtp, float* __restrict__ Out)
{
  __shared__ unsigned short ldsA[BM * BKg];
  __shared__ unsigned short ldsB[BN * BKg];
  const int tid = threadIdx.x;
  const int wid = tid >> 6;
  const int lane = tid & 63;
  const int lr = lane & 15, lg = lane >> 4;
  const int wr = wid >> 1, wc = wid & 1;
  const int m0 = blockIdx.y * BM, n0 = blockIdx.x * BN;

  const f32x4 vzero = {0.f, 0.f, 0.f, 0.f};
  f32x4 acc[4][4];
  #pragma unroll
  for (int i = 0; i < 4; ++i)
    #pragma unroll
    for (int j = 0; j < 4; ++j) acc[i][j] = vzero;

  for (int k0 = 0; k0 < K; k0 += BKg){
    __syncthreads();
    #pragma unroll
    for (int it = 0; it < 4; ++it){
      int c = it * 256 + tid;
      int row = c >> 3;
      int sc = (c & 7) ^ (row & 7);
      gl2lds16(A  + (size_t)(m0 + row) * K + k0 + sc * 8,
               (char*)ldsA + (it * 256 + wid * 64) * 16);
      gl2lds16(Bt + (size_t)(n0 + row) * K + k0 + sc * 8,
               (char*)ldsB + (it * 256 + wid * 64) * 16);
    }
    __syncthreads();
    #pragma unroll
    for (int kc = 0; kc < 2; ++kc){
      short8 af[4], bfr[4];
      #pragma unroll
      for (int i = 0; i < 4; ++i){
        int row = wr * 64 + i * 16 + lr;
        int off = row * 128 + lg * 16 + kc * 64;
        off ^= (row & 7) << 4;
        af[i] = *(const short8*)((const char*)ldsA + off);
      }
      #pragma unroll
      for (int j = 0; j < 4; ++j){
        int row = wc * 64 + j * 16 + lr;
        int off = row * 128 + lg * 16 + kc * 64;
        off ^= (row & 7) << 4;
        bfr[j] = *(const short8*)((const char*)ldsB + off);
      }
      #pragma unroll
      for (int i = 0; i < 4; ++i)
        #pragma unroll
        for (int j = 0; j < 4; ++j)
          acc[i][j] = __builtin_amdgcn_mfma_f32_16x16x32_bf16(af[i], bfr[j], acc[i][j], 0, 0, 0);
    }
  }

  if (mode == 0){
    const float qscale = 0.125f * 1.4426950408889634f;
    #pragma unroll
    for (int i = 0; i < 4; ++i)
      #pragma unroll
      for (int j = 0; j < 4; ++j)
        #pragma unroll
        for (int r = 0; r < 4; ++r){
          int gm = m0 + wr * 64 + i * 16 + lg * 4 + r;
          int gn = n0 + wc * 64 + j * 16 + lr;
          float v = acc[i][j][r] + bias[gn];
          int which = gn >> 10;
          int h = (gn >> 6) & 15;
          int hd = gn & 63;
          int b = gm >> 11;
          int s = gm & 2047;
          size_t bh = (size_t)(b * 16 + h);
          if (which == 0)      Qp[(bh * Ssz + s) * 64 + hd] = f2bf(v * qscale);
          else if (which == 1) Kp[(bh * Ssz + s) * 64 + hd] = f2bf(v);
          else                 Vtp[(bh * 64 + hd) * Ssz + s] = f2bf(v);
        }
  } else {
    #pragma unroll
    for (int i = 0; i < 4; ++i)
      #pragma unroll
      for (int j = 0; j < 4; ++j)
        #pragma unroll
        for (int r = 0; r < 4; ++r){
          int gm = m0 + wr * 64 + i * 16 + lg * 4 + r;
          int gn = n0 + wc * 64 + j * 16 + lr;
          Out[(size_t)gm * N + gn] = acc[i][j][r] + bias[gn];
        }
  }
}

// ---------------- causal flash attention, swapped-QK 32x32, KVBLK=128 + T5 setprio ----------------
// grid (8,64), 4 waves/block, XCD-local bh grouping (R10-proven). setprio(1) around
// MFMA clusters: independent blocks per CU -> scheduler favors MFMA-entering waves (m191).
__global__ __launch_bounds__(256, 2)
void attn_kernel(const unsigned short* __restrict__ Qp, const unsigned short* __restrict__ Kp,
                 const unsigned short* __restrict__ Vtp, unsigned short* __restrict__ Att)
{
  __shared__ unsigned short ldsK[2][8192];
  __shared__ unsigned short ldsV[2][8192];
  const int tid = threadIdx.x;
  const int wid = tid >> 6;
  const int lane = tid & 63;
  const int lq = lane & 31;
  const int hi = lane >> 5;

  const int flat = (int)blockIdx.x + 8 * (int)blockIdx.y;
  const int xcd = flat & 7;
  const int i6  = flat >> 3;
  const int bh  = xcd * 8 + (i6 >> 3);
  const int qx  = i6 & 7;
  const int b = bh >> 4, hh = bh & 15;

  #pragma unroll 1
  for (int job = 0; job < 2; ++job){
    const int qt = job ? (15 - qx) : qx;
    const int q0w = qt * 128 + wid * 32;
    const int qa = q0w + lq;
    const int nt = qt + 1;

    short8 qf[4];
    {
      const unsigned short* Qb = Qp + ((size_t)bh * Ssz + q0w + lq) * 64 + hi * 8;
      #pragma unroll
      for (int ks = 0; ks < 4; ++ks) qf[ks] = *(const short8*)(Qb + ks * 16);
    }

    f32x16 Ot[2];
    #pragma unroll
    for (int d = 0; d < 2; ++d)
      #pragma unroll
      for (int r = 0; r < 16; ++r) Ot[d][r] = 0.f;
    float mrun = -3e38f, lsum = 0.f;

    auto STAGE = [&](int kt, int buf){
      #pragma unroll
      for (int it = 0; it < 4; ++it){
        int c = it * 256 + tid;
        int rowK = c >> 3, scK = (c & 7) ^ (rowK & 7);
        gl2lds16(Kp + ((size_t)bh * Ssz + kt * 128 + rowK) * 64 + scK * 8,
                 (char*)&ldsK[buf][0] + c * 16);
        int rowV = c >> 4, scV = (c & 15) ^ (rowV & 7);
        gl2lds16(Vtp + ((size_t)bh * 64 + rowV) * Ssz + kt * 128 + scV * 8,
                 (char*)&ldsV[buf][0] + c * 16);
      }
    };

    STAGE(0, 0);
    __syncthreads();

    #pragma unroll 1
    for (int kt = 0; kt < nt; ++kt){
      const int cur = kt & 1;
      if (kt + 1 < nt) STAGE(kt + 1, cur ^ 1);

      if (kt * 128 <= q0w + 31){
        const char* Kb = (const char*)&ldsK[cur][0];
        const char* Vb = (const char*)&ldsV[cur][0];

        f32x16 S[4];
        #pragma unroll
        for (int kb = 0; kb < 4; ++kb)
          #pragma unroll
          for (int r = 0; r < 16; ++r) S[kb][r] = 0.f;
        __builtin_amdgcn_s_setprio(1);
        #pragma unroll
        for (int ks = 0; ks < 4; ++ks){
          int col = ks * 32 + hi * 16;
          #pragma unroll
          for (int kb = 0; kb < 4; ++kb){
            int row = kb * 32 + lq;
            short8 kfr = *(const short8*)(Kb + ((row * 128 + col) ^ ((row & 7) << 4)));
            S[kb] = __builtin_amdgcn_mfma_f32_32x32x16_bf16(kfr, qf[ks], S[kb], 0, 0, 0);
          }
        }
        __builtin_amdgcn_s_setprio(0);

        if (kt * 128 + 127 > q0w){
          #pragma unroll
          for (int r = 0; r < 16; ++r){
            int keyb = kt * 128 + (r & 3) + ((r >> 2) << 3) + 4 * hi;
            #pragma unroll
            for (int kb = 0; kb < 4; ++kb)
              if (keyb + kb * 32 > qa) S[kb][r] = -3e38f;
          }
        }

        float t16[16];
        #pragma unroll
        for (int r = 0; r < 16; ++r)
          t16[r] = fmaxf(fmaxf(S[0][r], S[1][r]), fmaxf(S[2][r], S[3][r]));
        float t8[8];
        #pragma unroll
        for (int r = 0; r < 8; ++r) t8[r] = fmaxf(t16[r], t16[r + 8]);
        float t4[4];
        #pragma unroll
        for (int r = 0; r < 4; ++r) t4[r] = fmaxf(t8[r], t8[r + 4]);
        float pmax = fmaxf(fmaxf(t4[0], t4[1]), fmaxf(t4[2], t4[3]));
        pmax = xmax64(pmax);

        if (!__all(pmax - mrun <= 8.0f)){
          float mn = fmaxf(mrun, pmax);
          float scl = __builtin_amdgcn_exp2f(mrun - mn);
          mrun = mn;
          lsum *= scl;
          #pragma unroll
          for (int d = 0; d < 2; ++d)
            #pragma unroll
            for (int r = 0; r < 16; ++r) Ot[d][r] *= scl;
        }

        #pragma unroll
        for (int kb = 0; kb < 4; ++kb)
          #pragma unroll
          for (int r = 0; r < 16; ++r)
            S[kb][r] = __builtin_amdgcn_exp2f(S[kb][r] - mrun);

        #pragma unroll
        for (int r = 0; r < 16; ++r)
          t16[r] = (S[0][r] + S[1][r]) + (S[2][r] + S[3][r]);
        #pragma unroll
        for (int r = 0; r < 8; ++r) t8[r] = t16[r] + t16[r + 8];
        #pragma unroll
        for (int r = 0; r < 4; ++r) t4[r] = t8[r] + t8[r + 4];
        float psum = (t4[0] + t4[1]) + (t4[2] + t4[3]);
        psum = xsum64(psum);
        lsum += psum;

        __builtin_amdgcn_s_setprio(1);
        #pragma unroll
        for (int s = 0; s < 8; ++s){
          const int kb = s >> 1, s1 = s & 1;
          unsigned u0 = cvtpk(S[kb][8 * s1 + 0], S[kb][8 * s1 + 1]);
          unsigned u1 = cvtpk(S[kb][8 * s1 + 2], S[kb][8 * s1 + 3]);
          unsigned u2 = cvtpk(S[kb][8 * s1 + 4], S[kb][8 * s1 + 5]);
          unsigned u3 = cvtpk(S[kb][8 * s1 + 6], S[kb][8 * s1 + 7]);
          permswap(u0, u2);
          permswap(u1, u3);
          union { unsigned u[4]; short8 s8; } pb;
          pb.u[0] = u0; pb.u[1] = u1; pb.u[2] = u2; pb.u[3] = u3;

          int col = s * 32 + hi * 16;   // V^T row is 256B
          int r0 = lq, r1 = 32 + lq;
          short8 v0 = *(const short8*)(Vb + (r0 * 256 + (col ^ ((r0 & 7) << 4))));
          short8 v1 = *(const short8*)(Vb + (r1 * 256 + (col ^ ((r1 & 7) << 4))));
          Ot[0] = __builtin_amdgcn_mfma_f32_32x32x16_bf16(v0, pb.s8, Ot[0], 0, 0, 0);
          Ot[1] = __builtin_amdgcn_mfma_f32_32x32x16_bf16(v1, pb.s8, Ot[1], 0, 0, 0);
        }
        __builtin_amdgcn_s_setprio(0);
      }
      __syncthreads();
    }

    // epilogue: O^T/lsum -> per-wave swizzled LDS transpose -> coalesced stores
    float inv = 1.0f / lsum;
    unsigned short* ep = &ldsK[0][0] + wid * 2048;
    #pragma unroll
    for (int d = 0; d < 2; ++d)
      #pragma unroll
      for (int g = 0; g < 4; ++g)
        #pragma unroll
        for (int cp = 0; cp < 2; ++cp){
          int r = g * 4 + cp * 2;
          unsigned w = cvtpk(Ot[d][r] * inv, Ot[d][r + 1] * inv);
          int dd = d * 32 + g * 8 + 4 * hi + cp * 2;
          int byte = lq * 128 + ((dd * 2) ^ ((lq & 7) << 4));
          *(unsigned*)((char*)ep + byte) = w;
        }
    __syncthreads();
    #pragma unroll
    for (int ii = 0; ii < 4; ++ii){
      int qr = ii * 8 + (lane >> 3);
      int cc = lane & 7;
      int byte = qr * 128 + ((cc * 16) ^ ((qr & 7) << 4));
      short8 vv = *(const short8*)((const char*)ep + byte);
      *(short8*)(Att + ((size_t)(b * Ssz + q0w + qr)) * Dsz + hh * 64 + cc * 8) = vv;
    }
    __syncthreads();
  }
}

extern "C" void kernel_launch(void* const* d_in, const int* in_sizes, int n_in,
                              void* d_out, int out_size, void* d_ws, size_t ws_size,
                              hipStream_t stream) {
  const float* x    = (const float*)d_in[0];
  const float* Wqkv = (const float*)d_in[1];
  const float* bqkv = (const float*)d_in[2];
  const float* Wout = (const float*)d_in[3];
  const float* bout = (const float*)d_in[4];
  float* out = (float*)d_out;

  unsigned short* xb    = (unsigned short*)d_ws;                 // 8192*1024
  unsigned short* wqkvT = xb    + (size_t)8192 * 1024;           // 3072*1024
  unsigned short* woutT = wqkvT + (size_t)3072 * 1024;           // 1024*1024
  unsigned short* Qb    = woutT + (size_t)1024 * 1024;           // [B,H,S,HD]
  unsigned short* Kb    = Qb    + (size_t)8388608;
  unsigned short* Vtb   = Kb    + (size_t)8388608;
  unsigned short* Attb  = Vtb   + (size_t)8388608;

  prep_kernel<<<8192, 256, 0, stream>>>(x, xb, Wqkv, wqkvT, Wout, woutT);
  gemm_bt<<<dim3(24, 64), 256, 0, stream>>>(xb, wqkvT, 8192, 3072, 1024,
                                            bqkv, 0, Qb, Kb, Vtb, nullptr);
  attn_kernel<<<dim3(8, 64), 256, 0, stream>>>(Qb, Kb, Vtb, Attb);
  gemm_bt<<<dim3(8, 64), 256, 0, stream>>>(Attb, woutT, 8192, 1024, 1024,
                                           bout, 1, nullptr, nullptr, nullptr, out);
}